// Round 5
// baseline (129.715 us; speedup 1.0000x reference)
//
#include <hip/hip_runtime.h>
#include <hip/hip_bf16.h>

// B=16, N=2048, DIM_X=512, DIM_E=64, F=576 (=512+64)
// out_b = Xe_b * (Wbig * (Xe_b^T x_b))  -- three NT-GEMMs, no NxN matrix.

typedef __attribute__((ext_vector_type(8))) short s16x8;
typedef __attribute__((ext_vector_type(4))) short s16x4;
typedef __attribute__((ext_vector_type(4))) float f32x4;

__device__ __forceinline__ unsigned short f2bf(float f) {
  union { float f; unsigned u; } v; v.f = f;
  unsigned r = v.u + 0x7fff + ((v.u >> 16) & 1);   // RNE
  return (unsigned short)(r >> 16);
}

// ---------------------------------------------------------------------------
// NT-GEMM: C[i][j] = sum_k A[i][k]*B[j][k]. A: MxK, B: NxK row-major bf16;
// C: MxN (bf16 or f32). TMxTN tile, TK=64, 256 threads = 4 waves (2x2).
// Pipeline (T3/T4 essence): depth-2 prefetch, 3 LDS buffers, ONE s_barrier
// per K-tile, counted s_waitcnt vmcnt(LPW) -- loads stay in flight across
// the barrier, never drained to 0 in the main loop. T5 setprio around MFMA.
// LDS swizzle both-sides (16B slot ^= row&7) via pre-swizzled global source.
// XCD batch grouping (bid&7 -> batches {x, x+8}).
// ---------------------------------------------------------------------------
template<int TM, int TN, int GX, int GY, int OUT_F32>
__global__ __launch_bounds__(256) void gemm_nt(
    const unsigned short* __restrict__ A, long sAb, int lda,
    const unsigned short* __restrict__ B, long sBb, int ldb,
    void* __restrict__ Cptr, long sCb, int ldc,
    int K)
{
  constexpr int TK = 64;
  constexpr int WM = TM / 2, WN = TN / 2;
  constexpr int AM = WM / 16, AN = WN / 16;
  constexpr int ACH = TM / 8;                 // 1024B chunks (8 rows) for A
  constexpr int BCH = TN / 8;
  constexpr int LPW = TM / 32 + TN / 32;      // global_load_lds per wave/tile
  constexpr int NBLK = GX * GY;
  static_assert(LPW == 5 || LPW == 6, "add a vmcnt case");

  __shared__ unsigned short As[3][TM * TK];
  __shared__ unsigned short Bs[3][TN * TK];

  const int bid  = blockIdx.x;
  const int xcd  = bid & 7;
  const int slot = bid >> 3;
  const int bz   = xcd + 8 * (slot / NBLK);
  const int tix  = slot % NBLK;
  const int m0   = (tix % GX) * TM;
  const int n0   = (tix / GX) * TN;

  const unsigned short* Ab = A + (long)bz * sAb;
  const unsigned short* Bb = B + (long)bz * sBb;

  const int tid  = threadIdx.x;
  const int lane = tid & 63;
  const int wave = tid >> 6;
  const int wm = (wave >> 1) * WM;
  const int wn = (wave & 1) * WN;
  const int fr = lane & 15;
  const int fg = lane >> 4;
  const int fx = fr & 7;

  const int srow = lane >> 3;
  const int scol = (((lane & 7) ^ (lane >> 3)) & 7) * 8;  // pre-swizzled src col

  f32x4 acc[AM][AN];
#pragma unroll
  for (int i = 0; i < AM; i++)
#pragma unroll
    for (int j = 0; j < AN; j++) acc[i][j] = (f32x4)(0.f);

  auto stage = [&](int buf, int k0) {
#pragma unroll
    for (int i = 0; i < ACH / 4; i++) {
      const int c = wave * (ACH / 4) + i;
      __builtin_amdgcn_global_load_lds(
          (const __attribute__((address_space(1))) unsigned*)
              (Ab + (long)(m0 + c * 8 + srow) * lda + k0 + scol),
          (__attribute__((address_space(3))) unsigned*)(&As[buf][c * 512]),
          16, 0, 0);
    }
#pragma unroll
    for (int i = 0; i < BCH / 4; i++) {
      const int c = wave * (BCH / 4) + i;
      __builtin_amdgcn_global_load_lds(
          (const __attribute__((address_space(1))) unsigned*)
              (Bb + (long)(n0 + c * 8 + srow) * ldb + k0 + scol),
          (__attribute__((address_space(3))) unsigned*)(&Bs[buf][c * 512]),
          16, 0, 0);
    }
  };

  auto compute = [&](int cur) {
    const unsigned short* Ac = &As[cur][0];
    const unsigned short* Bc = &Bs[cur][0];
    __builtin_amdgcn_s_setprio(1);
#pragma unroll
    for (int ks = 0; ks < 2; ks++) {
      s16x8 av[AM], bv[AN];
#pragma unroll
      for (int mt = 0; mt < AM; mt++)
        av[mt] = *(const s16x8*)
            &Ac[(wm + mt * 16 + fr) * TK + (((ks * 4 + fg) ^ fx) * 8)];
#pragma unroll
      for (int nt = 0; nt < AN; nt++)
        bv[nt] = *(const s16x8*)
            &Bc[(wn + nt * 16 + fr) * TK + (((ks * 4 + fg) ^ fx) * 8)];
#pragma unroll
      for (int mt = 0; mt < AM; mt++)
#pragma unroll
        for (int nt = 0; nt < AN; nt++)
          acc[mt][nt] = __builtin_amdgcn_mfma_f32_16x16x32_bf16(
              av[mt], bv[nt], acc[mt][nt], 0, 0, 0);
    }
    __builtin_amdgcn_s_setprio(0);
  };

  const int NT = K / TK;
  stage(0, 0);
  stage(1, TK);

  int t = 0;
  for (; t < NT - 1; ++t) {
    // retire this wave's oldest LPW loads (tile t); allow tile t+1 in flight
    if constexpr (LPW == 5)
      asm volatile("s_waitcnt vmcnt(5)" ::: "memory");
    else
      asm volatile("s_waitcnt vmcnt(6)" ::: "memory");
    __builtin_amdgcn_s_barrier();      // all waves' tile-t data now in LDS
    asm volatile("" ::: "memory");     // keep DMA/ds ops below the barrier
    if (t + 2 < NT) stage((t + 2) % 3, (t + 2) * TK);
    compute(t % 3);
  }
  asm volatile("s_waitcnt vmcnt(0)" ::: "memory");
  __builtin_amdgcn_s_barrier();
  asm volatile("" ::: "memory");
  compute(t % 3);

  // D layout (verified m89): col = lane&15, row = (lane>>4)*4 + j
  if (OUT_F32) {
    float* C = (float*)Cptr + (long)bz * sCb;
#pragma unroll
    for (int mt = 0; mt < AM; mt++) {
      const int row = m0 + wm + mt * 16 + fg * 4;
#pragma unroll
      for (int nt = 0; nt < AN; nt++) {
        const int col = n0 + wn + nt * 16 + fr;
#pragma unroll
        for (int j = 0; j < 4; j++)
          C[(long)(row + j) * ldc + col] = acc[mt][nt][j];
      }
    }
  } else {
    unsigned short* C = (unsigned short*)Cptr + (long)bz * sCb;
#pragma unroll
    for (int mt = 0; mt < AM; mt++) {
      const int row = m0 + wm + mt * 16 + fg * 4;
#pragma unroll
      for (int nt = 0; nt < AN; nt++) {
        const int col = n0 + wn + nt * 16 + fr;
#pragma unroll
        for (int j = 0; j < 4; j++)
          C[(long)(row + j) * ldc + col] = f2bf(acc[mt][nt][j]);
      }
    }
  }
}

// ---------------------------------------------------------------------------
// Fused convert: per 64x64 tile, read x/e (f32), write Xe (bf16) directly
// from registers, and XeT (bf16 transposed) via an LDS tile.
// ---------------------------------------------------------------------------
__global__ __launch_bounds__(256) void convert_fused(
    const float* __restrict__ x, const float* __restrict__ e,
    unsigned short* __restrict__ XeT, unsigned short* __restrict__ Xe)
{
  constexpr int LP = 66;             // row stride in elems (64 + 2 pad)
  __shared__ unsigned short t[64 * LP];
  const int b  = blockIdx.z;
  const int k0 = blockIdx.x * 64;
  const int f0 = blockIdx.y * 64;
  const int l  = threadIdx.x & 63;
  const int w  = threadIdx.x >> 6;
  const int fi = (l & 15) * 4;
  const int f  = f0 + fi;

#pragma unroll
  for (int it = 0; it < 4; ++it) {
    const int row = w * 16 + it * 4 + (l >> 4);
    const int k = k0 + row;
    float4 v = (f < 512) ? *(const float4*)&x[((long)b * 2048 + k) * 512 + f]
                         : *(const float4*)&e[(long)k * 64 + (f - 512)];
    s16x4 o; o[0] = f2bf(v.x); o[1] = f2bf(v.y); o[2] = f2bf(v.z); o[3] = f2bf(v.w);
    if (Xe) *(s16x4*)&Xe[((long)b * 2048 + k) * 576 + f] = o;
    *(s16x4*)&t[row * LP + fi] = o;
  }
  __syncthreads();
#pragma unroll
  for (int i = 0; i < 2; ++i) {
    const int c  = threadIdx.x + 256 * i;   // 0..511
    const int fr = c >> 3;                  // f row within tile
    const int kc = (c & 7) * 8;             // k chunk
    s16x8 o;
#pragma unroll
    for (int j = 0; j < 8; ++j) o[j] = t[(kc + j) * LP + fr];
    *(s16x8*)&XeT[((long)b * 576 + f0 + fr) * 2048 + k0 + kc] = o;
  }
}

// Xe only (fallback when workspace can't hold both XeT and Xe)
__global__ __launch_bounds__(256) void convert_xe(
    const float* __restrict__ x, const float* __restrict__ e,
    unsigned short* __restrict__ Xe)
{
  long g = (long)blockIdx.x * 256 + threadIdx.x;  // 16*2048*144 total
  int  c4 = (int)(g % 144);
  long bn = g / 144;
  int  n  = (int)(bn % 2048);
  int  f  = c4 * 4;
  float4 v = (f < 512) ? *(const float4*)&x[bn * 512 + f]
                       : *(const float4*)&e[(long)n * 64 + (f - 512)];
  s16x4 o; o[0] = f2bf(v.x); o[1] = f2bf(v.y); o[2] = f2bf(v.z); o[3] = f2bf(v.w);
  *(s16x4*)&Xe[bn * 576 + f] = o;
}

// ---------------------------------------------------------------------------
// Wb[m][k] (576x576 bf16) = quadrant-wise transpose of W0..W3 with
// relu(triu) on the W0 block. 32x32 LDS tiles; coalesced reads AND writes.
// ---------------------------------------------------------------------------
__global__ __launch_bounds__(256) void build_wb(
    const float* __restrict__ W0, const float* __restrict__ W1,
    const float* __restrict__ W2, const float* __restrict__ W3,
    unsigned short* __restrict__ Wb)
{
  __shared__ float tw[32][33];
  const int m0 = blockIdx.x * 32;
  const int k0 = blockIdx.y * 32;
  const int r  = threadIdx.x >> 3;        // 0..31
  const int c4 = (threadIdx.x & 7) * 4;   // 0..28

  const int k = k0 + r;
  float4 v;
  if (m0 < 512) {
    if (k0 < 512) v = *(const float4*)&W0[k * 512 + m0 + c4];
    else          v = *(const float4*)&W1[(k - 512) * 512 + m0 + c4];
  } else {
    if (k0 < 512) v = *(const float4*)&W2[k * 64 + (m0 - 512) + c4];
    else          v = *(const float4*)&W3[(k - 512) * 64 + (m0 - 512) + c4];
  }
  tw[r][c4 + 0] = v.x; tw[r][c4 + 1] = v.y; tw[r][c4 + 2] = v.z; tw[r][c4 + 3] = v.w;
  __syncthreads();

  const int m = m0 + r;
  const bool tri = (m0 < 512) && (k0 < 512);
  s16x4 o;
#pragma unroll
  for (int j = 0; j < 4; ++j) {
    const int kk = k0 + c4 + j;
    float val = tw[c4 + j][r];
    if (tri) val = (m > kk) ? fmaxf(val, 0.f) : 0.f;
    o[j] = f2bf(val);
  }
  *(s16x4*)&Wb[m * 576 + k0 + c4] = o;
}

// ---------------------------------------------------------------------------
extern "C" void kernel_launch(void* const* d_in, const int* in_sizes, int n_in,
                              void* d_out, int out_size, void* d_ws, size_t ws_size,
                              hipStream_t stream) {
  const float* x  = (const float*)d_in[0];
  const float* e  = (const float*)d_in[1];
  const float* W0 = (const float*)d_in[2];
  const float* W1 = (const float*)d_in[3];
  const float* W2 = (const float*)d_in[4];
  const float* W3 = (const float*)d_in[5];
  float* out = (float*)d_out;

  const size_t SZ_XeT = (size_t)16 * 576 * 2048 * 2;  // 37,748,736
  const size_t SZ_CT  = (size_t)16 * 512 * 576 * 2;   //  9,437,184
  const size_t SZ_DT  = SZ_CT;
  const size_t SZ_WB  = (size_t)576 * 576 * 2;        //    663,552

  char* p = (char*)d_ws;
  unsigned short* XeT = (unsigned short*)p;  p += SZ_XeT;
  unsigned short* CT  = (unsigned short*)p;  p += SZ_CT;
  unsigned short* DT  = (unsigned short*)p;  p += SZ_DT;
  unsigned short* Wb  = (unsigned short*)p;  p += SZ_WB;
  const size_t base = SZ_XeT + SZ_CT + SZ_DT + SZ_WB;
  if (ws_size < base) return;  // insufficient workspace -> loud failure
  const bool roomy = ws_size >= base + SZ_XeT;
  unsigned short* Xe = roomy ? (unsigned short*)p : XeT;

  build_wb<<<dim3(18, 18), 256, 0, stream>>>(W0, W1, W2, W3, Wb);
  convert_fused<<<dim3(32, 9, 16), 256, 0, stream>>>(x, e, XeT,
                                                     roomy ? Xe : nullptr);

  // Stage 1: CT[i][j] = sum_k XeT[i][k]*XeT[j][k]   (M=512, N=576, K=2048)
  gemm_nt<64, 96, 8, 6, 0><<<768, 256, 0, stream>>>(
      XeT, (long)576 * 2048, 2048,
      XeT, (long)576 * 2048, 2048,
      CT,  (long)512 * 576, 576, 2048);

  if (!roomy)
    convert_xe<<<18432, 256, 0, stream>>>(x, e, Xe);

  // Stage 2: DT[t][m] = sum_f CT[t][f]*Wb[m][f]     (M=512, N=576, K=576)
  gemm_nt<64, 96, 8, 6, 0><<<768, 256, 0, stream>>>(
      CT, (long)512 * 576, 576,
      Wb, 0L, 576,
      DT, (long)512 * 576, 576, 576);

  // Stage 3: out[n][t] = sum_m Xe[n][m]*DT[t][m]    (M=2048, N=512, K=576)
  gemm_nt<128, 64, 16, 8, 1><<<2048, 256, 0, stream>>>(
      Xe, (long)2048 * 576, 576,
      DT, (long)512 * 576, 576,
      out, (long)2048 * 512, 512, 576);
}

// Round 6
// 95.547 us; speedup vs baseline: 1.3576x; 1.3576x over previous
//
#include <hip/hip_runtime.h>
#include <hip/hip_bf16.h>

// B=16, N=2048, DIM_X=512, DIM_E=64, F=576 (=512+64)
// out_b = Xe_b * (Wbig * (Xe_b^T x_b))  -- three NT-GEMMs, no NxN matrix.

typedef __attribute__((ext_vector_type(8))) short s16x8;
typedef __attribute__((ext_vector_type(4))) short s16x4;
typedef __attribute__((ext_vector_type(4))) float f32x4;

__device__ __forceinline__ unsigned short f2bf(float f) {
  union { float f; unsigned u; } v; v.f = f;
  unsigned r = v.u + 0x7fff + ((v.u >> 16) & 1);   // RNE
  return (unsigned short)(r >> 16);
}

// ---------------------------------------------------------------------------
// NT-GEMM: C[i][j] = sum_k A[i][k]*B[j][k]. A: MxK, B: NxK row-major bf16;
// C: MxN (bf16 or f32). TMxTN tile, TK=64, 256 threads = 4 waves (2x2),
// wave tile TM/2 x TN/2. Proven round-3/4 loop: global_load_lds w16 staging,
// 2-buffer LDS, prefetch-before-compute, ONE __syncthreads per K-tile (its
// vmcnt(0) drain is the wait -- hand-scheduled counted vmcnt REGRESSED,
// round 5 / m141 / m230). LDS swizzle both-sides (16B slot ^= row&7) via
// pre-swizzled global source. XCD batch grouping (bid&7 -> batches {x,x+8}).
// ---------------------------------------------------------------------------
template<int TM, int TN, int GX, int GY, int OUT_F32>
__global__ __launch_bounds__(256) void gemm_nt(
    const unsigned short* __restrict__ A, long sAb, int lda,
    const unsigned short* __restrict__ B, long sBb, int ldb,
    void* __restrict__ Cptr, long sCb, int ldc,
    int K)
{
  constexpr int TK = 64;
  constexpr int WM = TM / 2, WN = TN / 2;
  constexpr int AM = WM / 16, AN = WN / 16;
  constexpr int ACH = TM / 8;                 // 1024B chunks (8 rows)
  constexpr int BCH = TN / 8;
  constexpr int NBLK = GX * GY;

  __shared__ unsigned short As[2][TM * TK];
  __shared__ unsigned short Bs[2][TN * TK];

  const int bid  = blockIdx.x;
  const int xcd  = bid & 7;
  const int slot = bid >> 3;
  const int bz   = xcd + 8 * (slot / NBLK);
  const int tix  = slot % NBLK;
  const int m0   = (tix % GX) * TM;
  const int n0   = (tix / GX) * TN;

  const unsigned short* Ab = A + (long)bz * sAb;
  const unsigned short* Bb = B + (long)bz * sBb;

  const int tid  = threadIdx.x;
  const int lane = tid & 63;
  const int wave = tid >> 6;
  const int wm = (wave >> 1) * WM;
  const int wn = (wave & 1) * WN;
  const int fr = lane & 15;
  const int fg = lane >> 4;
  const int fx = fr & 7;

  const int srow = lane >> 3;
  const int scol = (((lane & 7) ^ (lane >> 3)) & 7) * 8;  // pre-swizzled src col

  f32x4 acc[AM][AN];
#pragma unroll
  for (int i = 0; i < AM; i++)
#pragma unroll
    for (int j = 0; j < AN; j++) acc[i][j] = (f32x4)(0.f);

  auto stage = [&](int buf, int k0) {
#pragma unroll
    for (int i = 0; i < ACH / 4; i++) {
      const int c = wave * (ACH / 4) + i;
      __builtin_amdgcn_global_load_lds(
          (const __attribute__((address_space(1))) unsigned*)
              (Ab + (long)(m0 + c * 8 + srow) * lda + k0 + scol),
          (__attribute__((address_space(3))) unsigned*)(&As[buf][c * 512]),
          16, 0, 0);
    }
#pragma unroll
    for (int i = 0; i < BCH / 4; i++) {
      const int c = wave * (BCH / 4) + i;
      __builtin_amdgcn_global_load_lds(
          (const __attribute__((address_space(1))) unsigned*)
              (Bb + (long)(n0 + c * 8 + srow) * ldb + k0 + scol),
          (__attribute__((address_space(3))) unsigned*)(&Bs[buf][c * 512]),
          16, 0, 0);
    }
  };

  const int NT = K / TK;
  stage(0, 0);
  __syncthreads();

  for (int t = 0; t < NT; ++t) {
    const int cur = t & 1;
    if (t + 1 < NT) stage(cur ^ 1, (t + 1) * TK);

    const unsigned short* Ac = &As[cur][0];
    const unsigned short* Bc = &Bs[cur][0];
#pragma unroll
    for (int ks = 0; ks < 2; ks++) {
      s16x8 av[AM], bv[AN];
#pragma unroll
      for (int mt = 0; mt < AM; mt++)
        av[mt] = *(const s16x8*)
            &Ac[(wm + mt * 16 + fr) * TK + (((ks * 4 + fg) ^ fx) * 8)];
#pragma unroll
      for (int nt = 0; nt < AN; nt++)
        bv[nt] = *(const s16x8*)
            &Bc[(wn + nt * 16 + fr) * TK + (((ks * 4 + fg) ^ fx) * 8)];
#pragma unroll
      for (int mt = 0; mt < AM; mt++)
#pragma unroll
        for (int nt = 0; nt < AN; nt++)
          acc[mt][nt] = __builtin_amdgcn_mfma_f32_16x16x32_bf16(
              av[mt], bv[nt], acc[mt][nt], 0, 0, 0);
    }
    __syncthreads();
  }

  // D layout (verified m89): col = lane&15, row = (lane>>4)*4 + j
  if (OUT_F32) {
    float* C = (float*)Cptr + (long)bz * sCb;
#pragma unroll
    for (int mt = 0; mt < AM; mt++) {
      const int row = m0 + wm + mt * 16 + fg * 4;
#pragma unroll
      for (int nt = 0; nt < AN; nt++) {
        const int col = n0 + wn + nt * 16 + fr;
#pragma unroll
        for (int j = 0; j < 4; j++)
          C[(long)(row + j) * ldc + col] = acc[mt][nt][j];
      }
    }
  } else {
    unsigned short* C = (unsigned short*)Cptr + (long)bz * sCb;
#pragma unroll
    for (int mt = 0; mt < AM; mt++) {
      const int row = m0 + wm + mt * 16 + fg * 4;
#pragma unroll
      for (int nt = 0; nt < AN; nt++) {
        const int col = n0 + wn + nt * 16 + fr;
#pragma unroll
        for (int j = 0; j < 4; j++)
          C[(long)(row + j) * ldc + col] = f2bf(acc[mt][nt][j]);
      }
    }
  }
}

// ---------------------------------------------------------------------------
// Fused convert: per 64x64 tile, read x/e (f32), write Xe (bf16) directly
// from registers, and XeT (bf16 transposed) via an LDS tile.
// ---------------------------------------------------------------------------
__global__ __launch_bounds__(256) void convert_fused(
    const float* __restrict__ x, const float* __restrict__ e,
    unsigned short* __restrict__ XeT, unsigned short* __restrict__ Xe)
{
  constexpr int LP = 66;             // row stride in elems (64 + 2 pad)
  __shared__ unsigned short t[64 * LP];
  const int b  = blockIdx.z;
  const int k0 = blockIdx.x * 64;
  const int f0 = blockIdx.y * 64;
  const int l  = threadIdx.x & 63;
  const int w  = threadIdx.x >> 6;
  const int fi = (l & 15) * 4;
  const int f  = f0 + fi;

#pragma unroll
  for (int it = 0; it < 4; ++it) {
    const int row = w * 16 + it * 4 + (l >> 4);
    const int k = k0 + row;
    float4 v = (f < 512) ? *(const float4*)&x[((long)b * 2048 + k) * 512 + f]
                         : *(const float4*)&e[(long)k * 64 + (f - 512)];
    s16x4 o; o[0] = f2bf(v.x); o[1] = f2bf(v.y); o[2] = f2bf(v.z); o[3] = f2bf(v.w);
    if (Xe) *(s16x4*)&Xe[((long)b * 2048 + k) * 576 + f] = o;
    *(s16x4*)&t[row * LP + fi] = o;
  }
  __syncthreads();
#pragma unroll
  for (int i = 0; i < 2; ++i) {
    const int c  = threadIdx.x + 256 * i;   // 0..511
    const int fr = c >> 3;                  // f row within tile
    const int kc = (c & 7) * 8;             // k chunk
    s16x8 o;
#pragma unroll
    for (int j = 0; j < 8; ++j) o[j] = t[(kc + j) * LP + fr];
    *(s16x8*)&XeT[((long)b * 576 + f0 + fr) * 2048 + k0 + kc] = o;
  }
}

// Xe only (fallback when workspace can't hold both XeT and Xe)
__global__ __launch_bounds__(256) void convert_xe(
    const float* __restrict__ x, const float* __restrict__ e,
    unsigned short* __restrict__ Xe)
{
  long g = (long)blockIdx.x * 256 + threadIdx.x;  // 16*2048*144 total
  int  c4 = (int)(g % 144);
  long bn = g / 144;
  int  n  = (int)(bn % 2048);
  int  f  = c4 * 4;
  float4 v = (f < 512) ? *(const float4*)&x[bn * 512 + f]
                       : *(const float4*)&e[(long)n * 64 + (f - 512)];
  s16x4 o; o[0] = f2bf(v.x); o[1] = f2bf(v.y); o[2] = f2bf(v.z); o[3] = f2bf(v.w);
  *(s16x4*)&Xe[bn * 576 + f] = o;
}

// ---------------------------------------------------------------------------
// Wb[m][k] (576x576 bf16) = quadrant-wise transpose of W0..W3 with
// relu(triu) on the W0 block. 32x32 LDS tiles; coalesced reads AND writes.
// ---------------------------------------------------------------------------
__global__ __launch_bounds__(256) void build_wb(
    const float* __restrict__ W0, const float* __restrict__ W1,
    const float* __restrict__ W2, const float* __restrict__ W3,
    unsigned short* __restrict__ Wb)
{
  __shared__ float tw[32][33];
  const int m0 = blockIdx.x * 32;
  const int k0 = blockIdx.y * 32;
  const int r  = threadIdx.x >> 3;        // 0..31
  const int c4 = (threadIdx.x & 7) * 4;   // 0..28

  const int k = k0 + r;
  float4 v;
  if (m0 < 512) {
    if (k0 < 512) v = *(const float4*)&W0[k * 512 + m0 + c4];
    else          v = *(const float4*)&W1[(k - 512) * 512 + m0 + c4];
  } else {
    if (k0 < 512) v = *(const float4*)&W2[k * 64 + (m0 - 512) + c4];
    else          v = *(const float4*)&W3[(k - 512) * 64 + (m0 - 512) + c4];
  }
  tw[r][c4 + 0] = v.x; tw[r][c4 + 1] = v.y; tw[r][c4 + 2] = v.z; tw[r][c4 + 3] = v.w;
  __syncthreads();

  const int m = m0 + r;
  const bool tri = (m0 < 512) && (k0 < 512);
  s16x4 o;
#pragma unroll
  for (int j = 0; j < 4; ++j) {
    const int kk = k0 + c4 + j;
    float val = tw[c4 + j][r];
    if (tri) val = (m > kk) ? fmaxf(val, 0.f) : 0.f;
    o[j] = f2bf(val);
  }
  *(s16x4*)&Wb[m * 576 + k0 + c4] = o;
}

// ---------------------------------------------------------------------------
extern "C" void kernel_launch(void* const* d_in, const int* in_sizes, int n_in,
                              void* d_out, int out_size, void* d_ws, size_t ws_size,
                              hipStream_t stream) {
  const float* x  = (const float*)d_in[0];
  const float* e  = (const float*)d_in[1];
  const float* W0 = (const float*)d_in[2];
  const float* W1 = (const float*)d_in[3];
  const float* W2 = (const float*)d_in[4];
  const float* W3 = (const float*)d_in[5];
  float* out = (float*)d_out;

  const size_t SZ_XeT = (size_t)16 * 576 * 2048 * 2;  // 37,748,736
  const size_t SZ_CT  = (size_t)16 * 512 * 576 * 2;   //  9,437,184
  const size_t SZ_DT  = SZ_CT;
  const size_t SZ_WB  = (size_t)576 * 576 * 2;        //    663,552

  char* p = (char*)d_ws;
  unsigned short* XeT = (unsigned short*)p;  p += SZ_XeT;
  unsigned short* CT  = (unsigned short*)p;  p += SZ_CT;
  unsigned short* DT  = (unsigned short*)p;  p += SZ_DT;
  unsigned short* Wb  = (unsigned short*)p;  p += SZ_WB;
  const size_t base = SZ_XeT + SZ_CT + SZ_DT + SZ_WB;
  if (ws_size < base) return;  // insufficient workspace -> loud failure
  const bool roomy = ws_size >= base + SZ_XeT;
  unsigned short* Xe = roomy ? (unsigned short*)p : XeT;

  build_wb<<<dim3(18, 18), 256, 0, stream>>>(W0, W1, W2, W3, Wb);
  convert_fused<<<dim3(32, 9, 16), 256, 0, stream>>>(x, e, XeT,
                                                     roomy ? Xe : nullptr);

  // Stage 1: CT[i][j] = sum_k XeT[i][k]*XeT[j][k]   (M=512, N=576, K=2048)
  // 128x96 tile: wave 64x48, 12 MFMA / 7 ds_read (vs 6/5 at 64x96)
  gemm_nt<128, 96, 4, 6, 0><<<384, 256, 0, stream>>>(
      XeT, (long)576 * 2048, 2048,
      XeT, (long)576 * 2048, 2048,
      CT,  (long)512 * 576, 576, 2048);

  if (!roomy)
    convert_xe<<<18432, 256, 0, stream>>>(x, e, Xe);

  // Stage 2: DT[t][m] = sum_f CT[t][f]*Wb[m][f]     (M=512, N=576, K=576)
  gemm_nt<128, 96, 4, 6, 0><<<384, 256, 0, stream>>>(
      CT, (long)512 * 576, 576,
      Wb, 0L, 576,
      DT, (long)512 * 576, 576, 576);

  // Stage 3: out[n][t] = sum_m Xe[n][m]*DT[t][m]    (M=2048, N=512, K=576)
  gemm_nt<128, 128, 16, 4, 1><<<1024, 256, 0, stream>>>(
      Xe, (long)2048 * 576, 576,
      DT, (long)512 * 576, 576,
      out, (long)2048 * 512, 512, 576);
}